// Round 17
// baseline (253.206 us; speedup 1.0000x reference)
//
#include <hip/hip_runtime.h>
#include <hip/hip_bf16.h>

typedef __attribute__((ext_vector_type(8))) short short8;
typedef __attribute__((ext_vector_type(4))) short short4v;
typedef __attribute__((ext_vector_type(4))) float floatx4;
typedef __attribute__((ext_vector_type(2))) long longx2;
typedef __attribute__((ext_vector_type(2))) unsigned int uintx2;

#define NND 8192
#define DHID 512
#define TAU_INV 2.0f
#define CEXP 2.885390081777927f
#define E2 7.389056098930650f

__device__ inline unsigned short f2bf(float f) {
    union { float f; unsigned u; } v; v.f = f;
    unsigned r = v.u + 0x7FFFu + ((v.u >> 16) & 1u);
    return (unsigned short)(r >> 16);
}
__device__ inline float bf2f(short s) {
    union { unsigned u; float f; } v; v.u = ((unsigned)(unsigned short)s) << 16;
    return v.f;
}

__device__ inline void gload_lds16(const void* g, void* l) {
    __builtin_amdgcn_global_load_lds(
        (const __attribute__((address_space(1))) unsigned int*)g,
        (__attribute__((address_space(3))) unsigned int*)l,
        16, 0, 0);
}

__device__ inline short8 cvt8(floatx4 a, floatx4 b) {
    short8 o;
    o[0] = (short)f2bf(a[0]); o[1] = (short)f2bf(a[1]);
    o[2] = (short)f2bf(a[2]); o[3] = (short)f2bf(a[3]);
    o[4] = (short)f2bf(b[0]); o[5] = (short)f2bf(b[1]);
    o[6] = (short)f2bf(b[2]); o[7] = (short)f2bf(b[3]);
    return o;
}

// both weights in one launch: [K=512][N=512] -> out[n][k] bf16
__global__ void transpose_cast2(const float* __restrict__ a, const float* __restrict__ b,
                                short* __restrict__ oa, short* __restrict__ ob) {
    int idx = blockIdx.x * 256 + threadIdx.x;
    const float* in = (idx < 262144) ? a : b;
    short* out = (idx < 262144) ? oa : ob;
    idx &= 262143;
    int n = idx >> 9, k = idx & 511;
    out[(n << 9) + k] = (short)f2bf(in[(k << 9) + n]);
}

// ---------------- projection GEMM (NT, bf16 MFMA), 128x128 tile ----------------
// MODE 0: A = fp32 z (stacked z1/z2), reg-staged with cvt -> +bias, elu -> bf16
// MODE 1: A = bf16 hb, gload-staged -> +bias -> bf16
#define BK 32

template<int MODE>
__global__ __launch_bounds__(256, 2)
void gemm_nt(const float* __restrict__ Az1, const float* __restrict__ Az2,
             const short* __restrict__ Abf, const short* __restrict__ B,
             const float* __restrict__ bias, short* __restrict__ outBf)
{
    __shared__ short As[128 * BK];
    __shared__ short Bs[128 * BK];

    const int tid  = threadIdx.x;
    const int m0 = blockIdx.x * 128;
    const int n0 = blockIdx.y * 128;
    const int wave = tid >> 6;
    const int lane = tid & 63;
    const int wr   = wave >> 1;
    const int wc   = wave & 1;
    const int lrow = lane & 15;
    const int lk   = lane >> 4;
    const int swq  = (lk ^ ((lrow >> 1) & 3)) * 8;

    const int r0 = tid >> 2;
    const int qq = tid & 3;
    const int q  = qq ^ ((r0 >> 1) & 3);

    const float* Asrc = (MODE == 0)
        ? ((m0 < NND) ? Az1 + (size_t)m0 * 512 : Az2 + (size_t)(m0 - NND) * 512)
        : nullptr;

    floatx4 acc[4][4];
    floatx4 zero4 = {0.f, 0.f, 0.f, 0.f};
#pragma unroll
    for (int m = 0; m < 4; ++m)
#pragma unroll
        for (int n = 0; n < 4; ++n) acc[m][n] = zero4;

    for (int kt = 0; kt < 512 / BK; ++kt) {
        const int k0 = kt * BK;
        floatx4 a00, a01, a10, a11;
        if (MODE == 0) {
            const float* p0 = Asrc + (size_t)r0 * 512 + k0 + q * 8;
            const float* p1 = Asrc + (size_t)(r0 + 64) * 512 + k0 + q * 8;
            a00 = *(const floatx4*)p0;  a01 = *(const floatx4*)(p0 + 4);
            a10 = *(const floatx4*)p1;  a11 = *(const floatx4*)(p1 + 4);
        }
        __syncthreads();
        if (MODE == 0) {
            *(short8*)&As[r0 * 32 + qq * 8]        = cvt8(a00, a01);
            *(short8*)&As[(r0 + 64) * 32 + qq * 8] = cvt8(a10, a11);
            gload_lds16(B + (size_t)(n0 + r0) * 512 + k0 + q * 8,      &Bs[r0 * 32 + qq * 8]);
            gload_lds16(B + (size_t)(n0 + 64 + r0) * 512 + k0 + q * 8, &Bs[(r0 + 64) * 32 + qq * 8]);
        } else {
#pragma unroll
            for (int i = 0; i < 2; ++i) {
                const int r = i * 64 + r0;
                gload_lds16(Abf + (size_t)(m0 + r) * 512 + k0 + q * 8, &As[r * 32 + qq * 8]);
                gload_lds16(B   + (size_t)(n0 + r) * 512 + k0 + q * 8, &Bs[r * 32 + qq * 8]);
            }
        }
        __syncthreads();
        short8 fa[4], fb[4];
#pragma unroll
        for (int m = 0; m < 4; ++m)
            fa[m] = *(const short8*)(&As[(wr * 64 + m * 16 + lrow) * 32 + swq]);
#pragma unroll
        for (int n = 0; n < 4; ++n)
            fb[n] = *(const short8*)(&Bs[(wc * 64 + n * 16 + lrow) * 32 + swq]);
#pragma unroll
        for (int m = 0; m < 4; ++m)
#pragma unroll
            for (int n = 0; n < 4; ++n)
                acc[m][n] = __builtin_amdgcn_mfma_f32_16x16x32_bf16(fa[m], fb[n], acc[m][n], 0, 0, 0);
    }

#pragma unroll
    for (int m = 0; m < 4; ++m) {
#pragma unroll
        for (int n = 0; n < 4; ++n) {
            const int gj = n0 + wc * 64 + n * 16 + lrow;
            const float bj = bias[gj];
#pragma unroll
            for (int r = 0; r < 4; ++r) {
                const int gi = m0 + wr * 64 + m * 16 + lk * 4 + r;
                float v = acc[m][n][r] + bj;
                if (MODE == 0) v = v > 0.f ? v : expm1f(v);
                outBf[(size_t)gi * 512 + gj] = (short)f2bf(v);
            }
        }
    }
}

// ---------------- Gram kernel: fp8 e4m3, 256x256 tile, 8 waves, 4-phase/K-tile ----------------
// m201-template port: per phase {6 ds_read_b128 + 1 stage gload -> barrier ->
// setprio + 16 MFMA -> [phase3: counted vmcnt] -> barrier}. 3-buffer rotation,
// depth-2 prefetch, vmcnt(4) steady state. Column-major triangle over 64 block-rows.
// No atomics: LDS block-reduce + coalesced partials (slot=bj row-side, slot=bi col-side).

__global__ __launch_bounds__(512, 1)
void gemm_gram(const unsigned char* __restrict__ Q, float* __restrict__ gpart)
{
    __shared__ unsigned char As[3][256 * 64];   // 48 KB
    __shared__ unsigned char Bs[3][256 * 64];   // 48 KB

    const int tid = threadIdx.x;
    // column-major triangle decode over 64 block-rows: wg -> (bi, bj), bi <= bj
    const int wg = blockIdx.x;
    int bj = (int)((sqrtf(8.0f * (float)wg + 1.0f) - 1.0f) * 0.5f);
    if (bj < 0) bj = 0;
    if (bj > 63) bj = 63;
    while (bj > 0 && bj * (bj + 1) / 2 > wg) --bj;
    while ((bj + 1) * (bj + 2) / 2 <= wg) ++bj;
    const int bi = wg - bj * (bj + 1) / 2;
    const int m0 = bi * 256, n0 = bj * 256;

    const int wave = tid >> 6;
    const int lane = tid & 63;
    const int wr   = wave >> 2;          // 0..1 : 128-row half
    const int wc   = wave & 3;           // 0..3 : 64-col strip
    const int lrow = lane & 15;
    const int lk   = lane >> 4;

    const int sr = tid >> 2;             // 0..127
    const int qL = tid & 3;
    const int qG = qL ^ ((sr >> 1) & 3); // (sr+128)>>1 same &3

#define STAGE_G(buf, k0) do { \
    gload_lds16(Q + (size_t)(m0 + sr) * 512 + (k0) + qG * 16,       &As[buf][ sr        * 64 + qL * 16]); \
    gload_lds16(Q + (size_t)(m0 + 128 + sr) * 512 + (k0) + qG * 16, &As[buf][(sr + 128) * 64 + qL * 16]); \
    gload_lds16(Q + (size_t)(n0 + sr) * 512 + (k0) + qG * 16,       &Bs[buf][ sr        * 64 + qL * 16]); \
    gload_lds16(Q + (size_t)(n0 + 128 + sr) * 512 + (k0) + qG * 16, &Bs[buf][(sr + 128) * 64 + qL * 16]); \
} while (0)

#define STAGE_1(buf, k0, c) do { \
    if ((c) == 0) gload_lds16(Q + (size_t)(m0 + sr) * 512 + (k0) + qG * 16,       &As[buf][ sr        * 64 + qL * 16]); \
    if ((c) == 1) gload_lds16(Q + (size_t)(m0 + 128 + sr) * 512 + (k0) + qG * 16, &As[buf][(sr + 128) * 64 + qL * 16]); \
    if ((c) == 2) gload_lds16(Q + (size_t)(n0 + sr) * 512 + (k0) + qG * 16,       &Bs[buf][ sr        * 64 + qL * 16]); \
    if ((c) == 3) gload_lds16(Q + (size_t)(n0 + 128 + sr) * 512 + (k0) + qG * 16, &Bs[buf][(sr + 128) * 64 + qL * 16]); \
} while (0)

    floatx4 acc[8][4];
    floatx4 zero4 = {0.f, 0.f, 0.f, 0.f};
#pragma unroll
    for (int m = 0; m < 8; ++m)
#pragma unroll
        for (int n = 0; n < 4; ++n) acc[m][n] = zero4;

    // prologue: tiles 0,1 staged; wait tile 0 (4 oldest loads), tile 1 in flight
    STAGE_G(0, 0);
    STAGE_G(1, 64);
    asm volatile("s_waitcnt vmcnt(4)" ::: "memory");
    __builtin_amdgcn_s_barrier();

#pragma unroll
    for (int kt = 0; kt < 8; ++kt) {
        const int cur = kt % 3;
        const int nxt = (kt + 2) % 3;
#pragma unroll
        for (int ph = 0; ph < 4; ++ph) {
            const int mh = ph >> 1, nh = ph & 1;
            // ds-read this quadrant's fragments
            longx2 fa[4], fb[2];
#pragma unroll
            for (int n = 0; n < 2; ++n) {
                const int row = wc * 64 + (nh * 2 + n) * 16 + lrow;
                fb[n] = *(const longx2*)&Bs[cur][(row << 6) + ((lk ^ ((row >> 1) & 3)) << 4)];
            }
#pragma unroll
            for (int m = 0; m < 4; ++m) {
                const int row = wr * 128 + (mh * 4 + m) * 16 + lrow;
                fa[m] = *(const longx2*)&As[cur][(row << 6) + ((lk ^ ((row >> 1) & 3)) << 4)];
            }
            // stage one chunk of tile kt+2
            if (kt + 2 < 8) STAGE_1(nxt, (kt + 2) * 64, ph);
            __builtin_amdgcn_s_barrier();
            __builtin_amdgcn_s_setprio(1);
#pragma unroll
            for (int m = 0; m < 4; ++m)
#pragma unroll
                for (int n = 0; n < 2; ++n) {
                    acc[mh * 4 + m][nh * 2 + n] = __builtin_amdgcn_mfma_f32_16x16x32_fp8_fp8(
                        fa[m][0], fb[n][0], acc[mh * 4 + m][nh * 2 + n], 0, 0, 0);
                    acc[mh * 4 + m][nh * 2 + n] = __builtin_amdgcn_mfma_f32_16x16x32_fp8_fp8(
                        fa[m][1], fb[n][1], acc[mh * 4 + m][nh * 2 + n], 0, 0, 0);
                }
            __builtin_amdgcn_s_setprio(0);
            if (ph == 3) {
                if (kt < 6) asm volatile("s_waitcnt vmcnt(4)" ::: "memory");
                else        asm volatile("s_waitcnt vmcnt(0)" ::: "memory");
            }
            __builtin_amdgcn_s_barrier();
        }
    }
#undef STAGE_G
#undef STAGE_1

    // epilogue: exp2 + cross-lane reduce + LDS block-reduce (reuse dead As buffer)
    // lred[0..1023]    : row partials [wc][256]
    // lred[1024..1535] : col partials [wr][256]
    float* lred = (float*)&As[0][0];

    float colpart[4] = {0.f, 0.f, 0.f, 0.f};
#pragma unroll
    for (int m = 0; m < 8; ++m) {
        float rowpart[4] = {0.f, 0.f, 0.f, 0.f};
#pragma unroll
        for (int n = 0; n < 4; ++n) {
#pragma unroll
            for (int r = 0; r < 4; ++r) {
                float v = exp2f(acc[m][n][r] * CEXP);
                rowpart[r] += v;
                colpart[n] += v;
            }
        }
#pragma unroll
        for (int r = 0; r < 4; ++r) {
            float t = rowpart[r];
            t += __shfl_xor(t, 1);
            t += __shfl_xor(t, 2);
            t += __shfl_xor(t, 4);
            t += __shfl_xor(t, 8);
            if (lrow == 0) lred[wc * 256 + wr * 128 + m * 16 + lk * 4 + r] = t;
        }
    }
#pragma unroll
    for (int n = 0; n < 4; ++n) {
        float t = colpart[n];
        t += __shfl_xor(t, 16);
        t += __shfl_xor(t, 32);
        if (lk == 0) lred[1024 + wr * 256 + wc * 64 + n * 16 + lrow] = t;
    }
    __syncthreads();

    if (tid < 256) {
        gpart[(size_t)bj * (2 * NND) + m0 + tid] =
            lred[tid] + lred[256 + tid] + lred[512 + tid] + lred[768 + tid];
    } else if (m0 != n0) {
        const int c = tid - 256;
        gpart[(size_t)bi * (2 * NND) + n0 + c] = lred[1024 + c] + lred[1280 + c];
    }
}

// ---------------- reduce partials: rsG[i] = sum_s gpart[s][i] (64 slots) ----------------
__global__ void reduce_partials(const float* __restrict__ gpart, float* __restrict__ rsG) {
    const int i = blockIdx.x * 256 + threadIdx.x;
    float s = 0.f;
#pragma unroll 8
    for (int sl = 0; sl < 64; ++sl)
        s += gpart[(size_t)sl * (2 * NND) + i];
    rsG[i] = s;
}

// ---------------- fused normalize (rows i, i+8192) + diag dot -> fp8 (k-permuted) ----------------
__global__ void normalize_diag(const short* __restrict__ o, unsigned char* __restrict__ anq,
                               float* __restrict__ d12) {
    const int row = blockIdx.x;          // 0..8191
    const int t = threadIdx.x;           // 128 threads x 4 elems
    short4v va = ((const short4v*)(o + ((size_t)row << 9)))[t];
    short4v vb = ((const short4v*)(o + ((size_t)(row + NND) << 9)))[t];
    const float a0 = bf2f(va[0]), a1 = bf2f(va[1]), a2 = bf2f(va[2]), a3 = bf2f(va[3]);
    const float b0 = bf2f(vb[0]), b1 = bf2f(vb[1]), b2 = bf2f(vb[2]), b3 = bf2f(vb[3]);
    float ssa = a0 * a0 + a1 * a1 + a2 * a2 + a3 * a3;
    float ssb = b0 * b0 + b1 * b1 + b2 * b2 + b3 * b3;
    float sd  = a0 * b0 + a1 * b1 + a2 * b2 + a3 * b3;
    for (int m = 1; m < 64; m <<= 1) {
        ssa += __shfl_xor(ssa, m);
        ssb += __shfl_xor(ssb, m);
        sd  += __shfl_xor(sd, m);
    }
    __shared__ float part[6];
    if ((t & 63) == 0) {
        const int w = (t >> 6) * 3;
        part[w] = ssa; part[w + 1] = ssb; part[w + 2] = sd;
    }
    __syncthreads();
    const float sca = 1.f / fmaxf(sqrtf(part[0] + part[3]), 1e-12f);
    const float scb = 1.f / fmaxf(sqrtf(part[1] + part[4]), 1e-12f);
    if (t == 0) d12[row] = (part[2] + part[5]) * sca * scb;

    const int k = t * 4;
    const int bb = k >> 6, kk = k & 63;
    const int off = (bb << 6) + (((kk & 31) >> 3) << 4) + ((kk >> 5) << 3) + (kk & 7);
    int wa = __builtin_amdgcn_cvt_pk_fp8_f32(a0 * sca, a1 * sca, 0, false);
    wa = __builtin_amdgcn_cvt_pk_fp8_f32(a2 * sca, a3 * sca, wa, true);
    *(int*)(anq + (row << 9) + off) = wa;
    int wb = __builtin_amdgcn_cvt_pk_fp8_f32(b0 * scb, b1 * scb, 0, false);
    wb = __builtin_amdgcn_cvt_pk_fp8_f32(b2 * scb, b3 * scb, wb, true);
    *(int*)(anq + ((size_t)(row + NND) << 9) + off) = wb;
}

// ---------------- final loss reduction ----------------
__global__ void final_reduce(const float* __restrict__ rsG,
                             const float* __restrict__ d12, float* __restrict__ out) {
    float s = 0.f;
    for (int i = threadIdx.x; i < NND; i += 256) {
        const float den1 = rsG[i] - E2;
        const float den2 = rsG[i + NND] - E2;
        s += 0.5f * (logf(den1) + logf(den2)) - d12[i] * TAU_INV;
    }
    for (int m = 1; m < 64; m <<= 1) s += __shfl_xor(s, m);
    __shared__ float part[4];
    const int lane = threadIdx.x & 63, w = threadIdx.x >> 6;
    if (lane == 0) part[w] = s;
    __syncthreads();
    if (threadIdx.x == 0) out[0] = (part[0] + part[1] + part[2] + part[3]) / (float)NND;
}

// ---------------- launch ----------------
extern "C" void kernel_launch(void* const* d_in, const int* in_sizes, int n_in,
                              void* d_out, int out_size, void* d_ws, size_t ws_size,
                              hipStream_t stream) {
    const float* z1 = (const float*)d_in[0];
    const float* z2 = (const float*)d_in[1];
    const float* w1 = (const float*)d_in[3];
    const float* b1 = (const float*)d_in[4];
    const float* w2 = (const float*)d_in[5];
    const float* b2 = (const float*)d_in[6];
    float* out = (float*)d_out;

    char* p = (char*)d_ws;
    const size_t MATB = (size_t)2 * NND * DHID * 2;   // 16 MB stacked bf16 matrix
    short* hb  = (short*)p;  p += MATB;
    short* obuf = (short*)p; p += MATB;
    unsigned char* anq = (unsigned char*)p; p += (size_t)2 * NND * DHID;  // stacked fp8
    float* gpart = (float*)p; p += (size_t)64 * 2 * NND * 4;              // 4 MB partials
    short* w1t = (short*)p;  p += 512 * 512 * 2;
    short* w2t = (short*)p;  p += 512 * 512 * 2;
    float* rsG = (float*)p;  p += (size_t)2 * NND * 4;
    float* d12 = (float*)p;  p += NND * 4;
    if ((size_t)(p - (char*)d_ws) > ws_size) return;

    transpose_cast2<<<2048, 256, 0, stream>>>(w1, w2, w1t, w2t);
    gemm_nt<0><<<dim3(128, 4), 256, 0, stream>>>(z1, z2, nullptr, w1t, b1, hb);
    gemm_nt<1><<<dim3(128, 4), 256, 0, stream>>>(nullptr, nullptr, hb, w2t, b2, obuf);
    normalize_diag<<<NND, 128, 0, stream>>>(obuf, anq, d12);

    gemm_gram<<<2080, 512, 0, stream>>>(anq, gpart);
    reduce_partials<<<64, 256, 0, stream>>>(gpart, rsG);

    final_reduce<<<1, 256, 0, stream>>>(rsG, d12, out);
}

// Round 18
// 195.579 us; speedup vs baseline: 1.2947x; 1.2947x over previous
//
#include <hip/hip_runtime.h>
#include <hip/hip_bf16.h>

typedef __attribute__((ext_vector_type(8))) short short8;
typedef __attribute__((ext_vector_type(4))) short short4v;
typedef __attribute__((ext_vector_type(4))) float floatx4;
typedef __attribute__((ext_vector_type(2))) long longx2;
typedef __attribute__((ext_vector_type(2))) unsigned int uintx2;

#define NND 8192
#define DHID 512
#define TAU_INV 2.0f
#define CEXP 2.885390081777927f
#define E2 7.389056098930650f

__device__ inline unsigned short f2bf(float f) {
    union { float f; unsigned u; } v; v.f = f;
    unsigned r = v.u + 0x7FFFu + ((v.u >> 16) & 1u);
    return (unsigned short)(r >> 16);
}
__device__ inline float bf2f(short s) {
    union { unsigned u; float f; } v; v.u = ((unsigned)(unsigned short)s) << 16;
    return v.f;
}

__device__ inline void gload_lds16(const void* g, void* l) {
    __builtin_amdgcn_global_load_lds(
        (const __attribute__((address_space(1))) unsigned int*)g,
        (__attribute__((address_space(3))) unsigned int*)l,
        16, 0, 0);
}

__device__ inline short8 cvt8(floatx4 a, floatx4 b) {
    short8 o;
    o[0] = (short)f2bf(a[0]); o[1] = (short)f2bf(a[1]);
    o[2] = (short)f2bf(a[2]); o[3] = (short)f2bf(a[3]);
    o[4] = (short)f2bf(b[0]); o[5] = (short)f2bf(b[1]);
    o[6] = (short)f2bf(b[2]); o[7] = (short)f2bf(b[3]);
    return o;
}

// both weights in one launch: [K=512][N=512] -> out[n][k] bf16
__global__ void transpose_cast2(const float* __restrict__ a, const float* __restrict__ b,
                                short* __restrict__ oa, short* __restrict__ ob) {
    int idx = blockIdx.x * 256 + threadIdx.x;
    const float* in = (idx < 262144) ? a : b;
    short* out = (idx < 262144) ? oa : ob;
    idx &= 262143;
    int n = idx >> 9, k = idx & 511;
    out[(n << 9) + k] = (short)f2bf(in[(k << 9) + n]);
}

// ---------------- projection GEMM (NT, bf16 MFMA), 128x128 tile ----------------
// MODE 0: A = fp32 z (stacked z1/z2), reg-staged with cvt -> +bias, elu -> bf16
// MODE 1: A = bf16 hb, gload-staged -> +bias -> bf16
#define BK 32

template<int MODE>
__global__ __launch_bounds__(256, 2)
void gemm_nt(const float* __restrict__ Az1, const float* __restrict__ Az2,
             const short* __restrict__ Abf, const short* __restrict__ B,
             const float* __restrict__ bias, short* __restrict__ outBf)
{
    __shared__ short As[128 * BK];
    __shared__ short Bs[128 * BK];

    const int tid  = threadIdx.x;
    const int m0 = blockIdx.x * 128;
    const int n0 = blockIdx.y * 128;
    const int wave = tid >> 6;
    const int lane = tid & 63;
    const int wr   = wave >> 1;
    const int wc   = wave & 1;
    const int lrow = lane & 15;
    const int lk   = lane >> 4;
    const int swq  = (lk ^ ((lrow >> 1) & 3)) * 8;

    const int r0 = tid >> 2;
    const int qq = tid & 3;
    const int q  = qq ^ ((r0 >> 1) & 3);

    const float* Asrc = (MODE == 0)
        ? ((m0 < NND) ? Az1 + (size_t)m0 * 512 : Az2 + (size_t)(m0 - NND) * 512)
        : nullptr;

    floatx4 acc[4][4];
    floatx4 zero4 = {0.f, 0.f, 0.f, 0.f};
#pragma unroll
    for (int m = 0; m < 4; ++m)
#pragma unroll
        for (int n = 0; n < 4; ++n) acc[m][n] = zero4;

    for (int kt = 0; kt < 512 / BK; ++kt) {
        const int k0 = kt * BK;
        floatx4 a00, a01, a10, a11;
        if (MODE == 0) {
            const float* p0 = Asrc + (size_t)r0 * 512 + k0 + q * 8;
            const float* p1 = Asrc + (size_t)(r0 + 64) * 512 + k0 + q * 8;
            a00 = *(const floatx4*)p0;  a01 = *(const floatx4*)(p0 + 4);
            a10 = *(const floatx4*)p1;  a11 = *(const floatx4*)(p1 + 4);
        }
        __syncthreads();
        if (MODE == 0) {
            *(short8*)&As[r0 * 32 + qq * 8]        = cvt8(a00, a01);
            *(short8*)&As[(r0 + 64) * 32 + qq * 8] = cvt8(a10, a11);
            gload_lds16(B + (size_t)(n0 + r0) * 512 + k0 + q * 8,      &Bs[r0 * 32 + qq * 8]);
            gload_lds16(B + (size_t)(n0 + 64 + r0) * 512 + k0 + q * 8, &Bs[(r0 + 64) * 32 + qq * 8]);
        } else {
#pragma unroll
            for (int i = 0; i < 2; ++i) {
                const int r = i * 64 + r0;
                gload_lds16(Abf + (size_t)(m0 + r) * 512 + k0 + q * 8, &As[r * 32 + qq * 8]);
                gload_lds16(B   + (size_t)(n0 + r) * 512 + k0 + q * 8, &Bs[r * 32 + qq * 8]);
            }
        }
        __syncthreads();
        short8 fa[4], fb[4];
#pragma unroll
        for (int m = 0; m < 4; ++m)
            fa[m] = *(const short8*)(&As[(wr * 64 + m * 16 + lrow) * 32 + swq]);
#pragma unroll
        for (int n = 0; n < 4; ++n)
            fb[n] = *(const short8*)(&Bs[(wc * 64 + n * 16 + lrow) * 32 + swq]);
#pragma unroll
        for (int m = 0; m < 4; ++m)
#pragma unroll
            for (int n = 0; n < 4; ++n)
                acc[m][n] = __builtin_amdgcn_mfma_f32_16x16x32_bf16(fa[m], fb[n], acc[m][n], 0, 0, 0);
    }

#pragma unroll
    for (int m = 0; m < 4; ++m) {
#pragma unroll
        for (int n = 0; n < 4; ++n) {
            const int gj = n0 + wc * 64 + n * 16 + lrow;
            const float bj = bias[gj];
#pragma unroll
            for (int r = 0; r < 4; ++r) {
                const int gi = m0 + wr * 64 + m * 16 + lk * 4 + r;
                float v = acc[m][n][r] + bj;
                if (MODE == 0) v = v > 0.f ? v : expm1f(v);
                outBf[(size_t)gi * 512 + gj] = (short)f2bf(v);
            }
        }
    }
}

// ---------------- Gram kernel: fp8 e4m3, 128x128 tile, BK=64, 3-buffer counted-vmcnt ----------------
// (round-14 proven: 138 us, MfmaUtil 42%, 0 conflicts, no spill, 1004 TF effective)
__global__ __launch_bounds__(256, 3)
void gemm_gram(const unsigned char* __restrict__ Q, float* __restrict__ gpart)
{
    __shared__ unsigned char As[3][128 * 64];
    __shared__ unsigned char Bs[3][128 * 64];

    const int tid = threadIdx.x;
    // column-major triangle decode: wg -> (bi, bj), bi <= bj
    const int wg = blockIdx.x;
    int bj = (int)((sqrtf(8.0f * (float)wg + 1.0f) - 1.0f) * 0.5f);
    if (bj < 0) bj = 0;
    if (bj > 127) bj = 127;
    while (bj > 0 && bj * (bj + 1) / 2 > wg) --bj;
    while ((bj + 1) * (bj + 2) / 2 <= wg) ++bj;
    const int bi = wg - bj * (bj + 1) / 2;
    const int m0 = bi * 128, n0 = bj * 128;

    const int wave = tid >> 6;
    const int lane = tid & 63;
    const int wr   = wave >> 1;
    const int wc   = wave & 1;
    const int lrow = lane & 15;
    const int lk   = lane >> 4;

    const int sr = tid >> 2;          // 0..63
    const int qL = tid & 3;
    const int qG = qL ^ ((sr >> 1) & 3);

#define STAGE_G(buf, k0) do { \
    gload_lds16(Q + (size_t)(m0 + sr) * 512 + (k0) + qG * 16,      &As[buf][ sr       * 64 + qL * 16]); \
    gload_lds16(Q + (size_t)(m0 + 64 + sr) * 512 + (k0) + qG * 16, &As[buf][(sr + 64) * 64 + qL * 16]); \
    gload_lds16(Q + (size_t)(n0 + sr) * 512 + (k0) + qG * 16,      &Bs[buf][ sr       * 64 + qL * 16]); \
    gload_lds16(Q + (size_t)(n0 + 64 + sr) * 512 + (k0) + qG * 16, &Bs[buf][(sr + 64) * 64 + qL * 16]); \
} while (0)

    floatx4 acc[4][4];
    floatx4 zero4 = {0.f, 0.f, 0.f, 0.f};
#pragma unroll
    for (int m = 0; m < 4; ++m)
#pragma unroll
        for (int n = 0; n < 4; ++n) acc[m][n] = zero4;

    // prologue: 2 tiles in flight; wait only tile 0 (4 oldest loads)
    STAGE_G(0, 0);
    STAGE_G(1, 64);
    asm volatile("s_waitcnt vmcnt(4)" ::: "memory");
    __builtin_amdgcn_s_barrier();

#pragma unroll
    for (int kt = 0; kt < 8; ++kt) {
        const int cur = kt % 3;
        if (kt + 2 < 8) STAGE_G((kt + 2) % 3, (kt + 2) * 64);   // depth-2 prefetch
        longx2 fb[4];
#pragma unroll
        for (int n = 0; n < 4; ++n) {
            const int row = wc * 64 + n * 16 + lrow;
            fb[n] = *(const longx2*)&Bs[cur][(row << 6) + ((lk ^ ((row >> 1) & 3)) << 4)];
        }
#pragma unroll
        for (int m = 0; m < 4; ++m) {
            const int row = wr * 64 + m * 16 + lrow;
            const longx2 fa = *(const longx2*)&As[cur][(row << 6) + ((lk ^ ((row >> 1) & 3)) << 4)];
#pragma unroll
            for (int n = 0; n < 4; ++n) {
                acc[m][n] = __builtin_amdgcn_mfma_f32_16x16x32_fp8_fp8(fa[0], fb[n][0], acc[m][n], 0, 0, 0);
                acc[m][n] = __builtin_amdgcn_mfma_f32_16x16x32_fp8_fp8(fa[1], fb[n][1], acc[m][n], 0, 0, 0);
            }
        }
        if (kt < 6) asm volatile("s_waitcnt vmcnt(4)" ::: "memory");
        else        asm volatile("s_waitcnt vmcnt(0)" ::: "memory");
        __builtin_amdgcn_s_barrier();
    }
#undef STAGE_G

    // epilogue: exp2 + cross-lane reduce + LDS block-reduce (reuse dead As staging buffer)
    float* lred = (float*)&As[0][0];

    float colpart[4] = {0.f, 0.f, 0.f, 0.f};
#pragma unroll
    for (int m = 0; m < 4; ++m) {
        float rowpart[4] = {0.f, 0.f, 0.f, 0.f};
#pragma unroll
        for (int n = 0; n < 4; ++n) {
#pragma unroll
            for (int r = 0; r < 4; ++r) {
                float v = exp2f(acc[m][n][r] * CEXP);
                rowpart[r] += v;
                colpart[n] += v;
            }
        }
#pragma unroll
        for (int r = 0; r < 4; ++r) {
            float t = rowpart[r];
            t += __shfl_xor(t, 1);
            t += __shfl_xor(t, 2);
            t += __shfl_xor(t, 4);
            t += __shfl_xor(t, 8);
            if (lrow == 0) lred[wc * 128 + wr * 64 + m * 16 + lk * 4 + r] = t;
        }
    }
#pragma unroll
    for (int n = 0; n < 4; ++n) {
        float t = colpart[n];
        t += __shfl_xor(t, 16);
        t += __shfl_xor(t, 32);
        if (lk == 0) lred[256 + wr * 128 + wc * 64 + n * 16 + lrow] = t;
    }
    __syncthreads();

    if (tid < 128) {
        gpart[(size_t)bj * (2 * NND) + m0 + tid] = lred[tid] + lred[128 + tid];
    } else if (m0 != n0) {
        const int c = tid - 128;
        gpart[(size_t)bi * (2 * NND) + n0 + c] = lred[256 + c] + lred[384 + c];
    }
}

// ---------------- reduce partials: rsG[i] = sum_s gpart[s][i] (128 slots) ----------------
__global__ void reduce_partials(const float* __restrict__ gpart, float* __restrict__ rsG) {
    const int i = blockIdx.x * 256 + threadIdx.x;
    float s = 0.f;
#pragma unroll 8
    for (int sl = 0; sl < 128; ++sl)
        s += gpart[(size_t)sl * (2 * NND) + i];
    rsG[i] = s;
}

// ---------------- fused normalize (rows i, i+8192) + diag dot -> fp8 (k-permuted) ----------------
__global__ void normalize_diag(const short* __restrict__ o, unsigned char* __restrict__ anq,
                               float* __restrict__ d12) {
    const int row = blockIdx.x;          // 0..8191
    const int t = threadIdx.x;           // 128 threads x 4 elems
    short4v va = ((const short4v*)(o + ((size_t)row << 9)))[t];
    short4v vb = ((const short4v*)(o + ((size_t)(row + NND) << 9)))[t];
    const float a0 = bf2f(va[0]), a1 = bf2f(va[1]), a2 = bf2f(va[2]), a3 = bf2f(va[3]);
    const float b0 = bf2f(vb[0]), b1 = bf2f(vb[1]), b2 = bf2f(vb[2]), b3 = bf2f(vb[3]);
    float ssa = a0 * a0 + a1 * a1 + a2 * a2 + a3 * a3;
    float ssb = b0 * b0 + b1 * b1 + b2 * b2 + b3 * b3;
    float sd  = a0 * b0 + a1 * b1 + a2 * b2 + a3 * b3;
    for (int m = 1; m < 64; m <<= 1) {
        ssa += __shfl_xor(ssa, m);
        ssb += __shfl_xor(ssb, m);
        sd  += __shfl_xor(sd, m);
    }
    __shared__ float part[6];
    if ((t & 63) == 0) {
        const int w = (t >> 6) * 3;
        part[w] = ssa; part[w + 1] = ssb; part[w + 2] = sd;
    }
    __syncthreads();
    const float sca = 1.f / fmaxf(sqrtf(part[0] + part[3]), 1e-12f);
    const float scb = 1.f / fmaxf(sqrtf(part[1] + part[4]), 1e-12f);
    if (t == 0) d12[row] = (part[2] + part[5]) * sca * scb;

    // permuted store: k-tile b (64), within: s = kk>>5, granule g = (kk&31)>>3, o = kk&7
    const int k = t * 4;
    const int bb = k >> 6, kk = k & 63;
    const int off = (bb << 6) + (((kk & 31) >> 3) << 4) + ((kk >> 5) << 3) + (kk & 7);
    int wa = __builtin_amdgcn_cvt_pk_fp8_f32(a0 * sca, a1 * sca, 0, false);
    wa = __builtin_amdgcn_cvt_pk_fp8_f32(a2 * sca, a3 * sca, wa, true);
    *(int*)(anq + (row << 9) + off) = wa;
    int wb = __builtin_amdgcn_cvt_pk_fp8_f32(b0 * scb, b1 * scb, 0, false);
    wb = __builtin_amdgcn_cvt_pk_fp8_f32(b2 * scb, b3 * scb, wb, true);
    *(int*)(anq + ((size_t)(row + NND) << 9) + off) = wb;
}

// ---------------- final loss reduction ----------------
__global__ void final_reduce(const float* __restrict__ rsG,
                             const float* __restrict__ d12, float* __restrict__ out) {
    float s = 0.f;
    for (int i = threadIdx.x; i < NND; i += 256) {
        const float den1 = rsG[i] - E2;
        const float den2 = rsG[i + NND] - E2;
        s += 0.5f * (logf(den1) + logf(den2)) - d12[i] * TAU_INV;
    }
    for (int m = 1; m < 64; m <<= 1) s += __shfl_xor(s, m);
    __shared__ float part[4];
    const int lane = threadIdx.x & 63, w = threadIdx.x >> 6;
    if (lane == 0) part[w] = s;
    __syncthreads();
    if (threadIdx.x == 0) out[0] = (part[0] + part[1] + part[2] + part[3]) / (float)NND;
}

// ---------------- launch ----------------
extern "C" void kernel_launch(void* const* d_in, const int* in_sizes, int n_in,
                              void* d_out, int out_size, void* d_ws, size_t ws_size,
                              hipStream_t stream) {
    const float* z1 = (const float*)d_in[0];
    const float* z2 = (const float*)d_in[1];
    const float* w1 = (const float*)d_in[3];
    const float* b1 = (const float*)d_in[4];
    const float* w2 = (const float*)d_in[5];
    const float* b2 = (const float*)d_in[6];
    float* out = (float*)d_out;

    char* p = (char*)d_ws;
    const size_t MATB = (size_t)2 * NND * DHID * 2;   // 16 MB stacked bf16 matrix
    short* hb  = (short*)p;  p += MATB;
    short* obuf = (short*)p; p += MATB;
    unsigned char* anq = (unsigned char*)p; p += (size_t)2 * NND * DHID;  // stacked fp8
    float* gpart = (float*)p; p += (size_t)128 * 2 * NND * 4;             // 8 MB partials
    short* w1t = (short*)p;  p += 512 * 512 * 2;
    short* w2t = (short*)p;  p += 512 * 512 * 2;
    float* rsG = (float*)p;  p += (size_t)2 * NND * 4;
    float* d12 = (float*)p;  p += NND * 4;
    if ((size_t)(p - (char*)d_ws) > ws_size) return;

    transpose_cast2<<<2048, 256, 0, stream>>>(w1, w2, w1t, w2t);
    gemm_nt<0><<<dim3(128, 4), 256, 0, stream>>>(z1, z2, nullptr, w1t, b1, hb);
    gemm_nt<1><<<dim3(128, 4), 256, 0, stream>>>(nullptr, nullptr, hb, w2t, b2, obuf);
    normalize_diag<<<NND, 128, 0, stream>>>(obuf, anq, d12);

    gemm_gram<<<8256, 256, 0, stream>>>(anq, gpart);
    reduce_partials<<<64, 256, 0, stream>>>(gpart, rsG);

    final_reduce<<<1, 256, 0, stream>>>(rsG, d12, out);
}

// Round 19
// 189.731 us; speedup vs baseline: 1.3346x; 1.0308x over previous
//
#include <hip/hip_runtime.h>
#include <hip/hip_bf16.h>

typedef __attribute__((ext_vector_type(8))) short short8;
typedef __attribute__((ext_vector_type(4))) short short4v;
typedef __attribute__((ext_vector_type(4))) float floatx4;
typedef __attribute__((ext_vector_type(2))) long longx2;
typedef __attribute__((ext_vector_type(2))) unsigned int uintx2;

#define NND 8192
#define DHID 512
#define TAU_INV 2.0f
#define CEXP 2.885390081777927f
#define E2 7.389056098930650f

__device__ inline unsigned short f2bf(float f) {
    union { float f; unsigned u; } v; v.f = f;
    unsigned r = v.u + 0x7FFFu + ((v.u >> 16) & 1u);
    return (unsigned short)(r >> 16);
}
__device__ inline float bf2f(short s) {
    union { unsigned u; float f; } v; v.u = ((unsigned)(unsigned short)s) << 16;
    return v.f;
}

__device__ inline void gload_lds16(const void* g, void* l) {
    __builtin_amdgcn_global_load_lds(
        (const __attribute__((address_space(1))) unsigned int*)g,
        (__attribute__((address_space(3))) unsigned int*)l,
        16, 0, 0);
}

__device__ inline short8 cvt8(floatx4 a, floatx4 b) {
    short8 o;
    o[0] = (short)f2bf(a[0]); o[1] = (short)f2bf(a[1]);
    o[2] = (short)f2bf(a[2]); o[3] = (short)f2bf(a[3]);
    o[4] = (short)f2bf(b[0]); o[5] = (short)f2bf(b[1]);
    o[6] = (short)f2bf(b[2]); o[7] = (short)f2bf(b[3]);
    return o;
}

// ---------------- LDS-tiled transpose+cast: [K=512][N=512] fp32 -> out[n][k] bf16 ----------------
// grid: 128 blocks (64 tiles per weight x 2 weights), 256 threads; 64x64 tile per block.
// Coalesced reads (consecutive n) and coalesced writes (consecutive k).
__global__ void transpose_cast2(const float* __restrict__ a, const float* __restrict__ b,
                                short* __restrict__ oa, short* __restrict__ ob) {
    __shared__ float tile[64][65];
    const int blk = blockIdx.x;
    const float* in = (blk < 64) ? a : b;
    short* out = (blk < 64) ? oa : ob;
    const int t64 = blk & 63;
    const int k0 = (t64 >> 3) * 64;    // tile origin in K
    const int n0 = (t64 & 7) * 64;     // tile origin in N
    const int tr = threadIdx.x >> 6;   // 0..3
    const int tc = threadIdx.x & 63;   // 0..63
#pragma unroll
    for (int i = 0; i < 16; ++i) {
        const int r = tr * 16 + i;     // row within tile (k)
        tile[r][tc] = in[(size_t)(k0 + r) * 512 + n0 + tc];
    }
    __syncthreads();
#pragma unroll
    for (int i = 0; i < 16; ++i) {
        const int r = tr * 16 + i;     // row within tile (n)
        out[(size_t)(n0 + r) * 512 + k0 + tc] = (short)f2bf(tile[tc][r]);
    }
}

// ---------------- projection GEMM (NT, bf16 MFMA), 128x128 tile ----------------
// MODE 0: A = fp32 z (stacked z1/z2), reg-staged with cvt -> +bias, elu -> bf16
// MODE 1: A = bf16 hb, gload-staged -> +bias -> bf16
#define BK 32

template<int MODE>
__global__ __launch_bounds__(256, 2)
void gemm_nt(const float* __restrict__ Az1, const float* __restrict__ Az2,
             const short* __restrict__ Abf, const short* __restrict__ B,
             const float* __restrict__ bias, short* __restrict__ outBf)
{
    __shared__ short As[128 * BK];
    __shared__ short Bs[128 * BK];

    const int tid  = threadIdx.x;
    const int m0 = blockIdx.x * 128;
    const int n0 = blockIdx.y * 128;
    const int wave = tid >> 6;
    const int lane = tid & 63;
    const int wr   = wave >> 1;
    const int wc   = wave & 1;
    const int lrow = lane & 15;
    const int lk   = lane >> 4;
    const int swq  = (lk ^ ((lrow >> 1) & 3)) * 8;

    const int r0 = tid >> 2;
    const int qq = tid & 3;
    const int q  = qq ^ ((r0 >> 1) & 3);

    const float* Asrc = (MODE == 0)
        ? ((m0 < NND) ? Az1 + (size_t)m0 * 512 : Az2 + (size_t)(m0 - NND) * 512)
        : nullptr;

    floatx4 acc[4][4];
    floatx4 zero4 = {0.f, 0.f, 0.f, 0.f};
#pragma unroll
    for (int m = 0; m < 4; ++m)
#pragma unroll
        for (int n = 0; n < 4; ++n) acc[m][n] = zero4;

    for (int kt = 0; kt < 512 / BK; ++kt) {
        const int k0 = kt * BK;
        floatx4 a00, a01, a10, a11;
        if (MODE == 0) {
            const float* p0 = Asrc + (size_t)r0 * 512 + k0 + q * 8;
            const float* p1 = Asrc + (size_t)(r0 + 64) * 512 + k0 + q * 8;
            a00 = *(const floatx4*)p0;  a01 = *(const floatx4*)(p0 + 4);
            a10 = *(const floatx4*)p1;  a11 = *(const floatx4*)(p1 + 4);
        }
        __syncthreads();
        if (MODE == 0) {
            *(short8*)&As[r0 * 32 + qq * 8]        = cvt8(a00, a01);
            *(short8*)&As[(r0 + 64) * 32 + qq * 8] = cvt8(a10, a11);
            gload_lds16(B + (size_t)(n0 + r0) * 512 + k0 + q * 8,      &Bs[r0 * 32 + qq * 8]);
            gload_lds16(B + (size_t)(n0 + 64 + r0) * 512 + k0 + q * 8, &Bs[(r0 + 64) * 32 + qq * 8]);
        } else {
#pragma unroll
            for (int i = 0; i < 2; ++i) {
                const int r = i * 64 + r0;
                gload_lds16(Abf + (size_t)(m0 + r) * 512 + k0 + q * 8, &As[r * 32 + qq * 8]);
                gload_lds16(B   + (size_t)(n0 + r) * 512 + k0 + q * 8, &Bs[r * 32 + qq * 8]);
            }
        }
        __syncthreads();
        short8 fa[4], fb[4];
#pragma unroll
        for (int m = 0; m < 4; ++m)
            fa[m] = *(const short8*)(&As[(wr * 64 + m * 16 + lrow) * 32 + swq]);
#pragma unroll
        for (int n = 0; n < 4; ++n)
            fb[n] = *(const short8*)(&Bs[(wc * 64 + n * 16 + lrow) * 32 + swq]);
#pragma unroll
        for (int m = 0; m < 4; ++m)
#pragma unroll
            for (int n = 0; n < 4; ++n)
                acc[m][n] = __builtin_amdgcn_mfma_f32_16x16x32_bf16(fa[m], fb[n], acc[m][n], 0, 0, 0);
    }

#pragma unroll
    for (int m = 0; m < 4; ++m) {
#pragma unroll
        for (int n = 0; n < 4; ++n) {
            const int gj = n0 + wc * 64 + n * 16 + lrow;
            const float bj = bias[gj];
#pragma unroll
            for (int r = 0; r < 4; ++r) {
                const int gi = m0 + wr * 64 + m * 16 + lk * 4 + r;
                float v = acc[m][n][r] + bj;
                if (MODE == 0) v = v > 0.f ? v : expm1f(v);
                outBf[(size_t)gi * 512 + gj] = (short)f2bf(v);
            }
        }
    }
}

// ---------------- Gram kernel: fp8 e4m3, 128x128 tile, BK=64, 3-buffer counted-vmcnt ----------------
// (round-14 proven: 138 us, MfmaUtil 42%, 0 conflicts, no spill, 1004 TF effective)
__global__ __launch_bounds__(256, 3)
void gemm_gram(const unsigned char* __restrict__ Q, float* __restrict__ gpart)
{
    __shared__ unsigned char As[3][128 * 64];
    __shared__ unsigned char Bs[3][128 * 64];

    const int tid = threadIdx.x;
    // column-major triangle decode: wg -> (bi, bj), bi <= bj
    const int wg = blockIdx.x;
    int bj = (int)((sqrtf(8.0f * (float)wg + 1.0f) - 1.0f) * 0.5f);
    if (bj < 0) bj = 0;
    if (bj > 127) bj = 127;
    while (bj > 0 && bj * (bj + 1) / 2 > wg) --bj;
    while ((bj + 1) * (bj + 2) / 2 <= wg) ++bj;
    const int bi = wg - bj * (bj + 1) / 2;
    const int m0 = bi * 128, n0 = bj * 128;

    const int wave = tid >> 6;
    const int lane = tid & 63;
    const int wr   = wave >> 1;
    const int wc   = wave & 1;
    const int lrow = lane & 15;
    const int lk   = lane >> 4;

    const int sr = tid >> 2;          // 0..63
    const int qL = tid & 3;
    const int qG = qL ^ ((sr >> 1) & 3);

#define STAGE_G(buf, k0) do { \
    gload_lds16(Q + (size_t)(m0 + sr) * 512 + (k0) + qG * 16,      &As[buf][ sr       * 64 + qL * 16]); \
    gload_lds16(Q + (size_t)(m0 + 64 + sr) * 512 + (k0) + qG * 16, &As[buf][(sr + 64) * 64 + qL * 16]); \
    gload_lds16(Q + (size_t)(n0 + sr) * 512 + (k0) + qG * 16,      &Bs[buf][ sr       * 64 + qL * 16]); \
    gload_lds16(Q + (size_t)(n0 + 64 + sr) * 512 + (k0) + qG * 16, &Bs[buf][(sr + 64) * 64 + qL * 16]); \
} while (0)

    floatx4 acc[4][4];
    floatx4 zero4 = {0.f, 0.f, 0.f, 0.f};
#pragma unroll
    for (int m = 0; m < 4; ++m)
#pragma unroll
        for (int n = 0; n < 4; ++n) acc[m][n] = zero4;

    // prologue: 2 tiles in flight; wait only tile 0 (4 oldest loads)
    STAGE_G(0, 0);
    STAGE_G(1, 64);
    asm volatile("s_waitcnt vmcnt(4)" ::: "memory");
    __builtin_amdgcn_s_barrier();

#pragma unroll
    for (int kt = 0; kt < 8; ++kt) {
        const int cur = kt % 3;
        if (kt + 2 < 8) STAGE_G((kt + 2) % 3, (kt + 2) * 64);   // depth-2 prefetch
        longx2 fb[4];
#pragma unroll
        for (int n = 0; n < 4; ++n) {
            const int row = wc * 64 + n * 16 + lrow;
            fb[n] = *(const longx2*)&Bs[cur][(row << 6) + ((lk ^ ((row >> 1) & 3)) << 4)];
        }
#pragma unroll
        for (int m = 0; m < 4; ++m) {
            const int row = wr * 64 + m * 16 + lrow;
            const longx2 fa = *(const longx2*)&As[cur][(row << 6) + ((lk ^ ((row >> 1) & 3)) << 4)];
#pragma unroll
            for (int n = 0; n < 4; ++n) {
                acc[m][n] = __builtin_amdgcn_mfma_f32_16x16x32_fp8_fp8(fa[0], fb[n][0], acc[m][n], 0, 0, 0);
                acc[m][n] = __builtin_amdgcn_mfma_f32_16x16x32_fp8_fp8(fa[1], fb[n][1], acc[m][n], 0, 0, 0);
            }
        }
        if (kt < 6) asm volatile("s_waitcnt vmcnt(4)" ::: "memory");
        else        asm volatile("s_waitcnt vmcnt(0)" ::: "memory");
        __builtin_amdgcn_s_barrier();
    }
#undef STAGE_G

    // epilogue: exp2 + cross-lane reduce + LDS block-reduce (reuse dead As staging buffer)
    float* lred = (float*)&As[0][0];

    float colpart[4] = {0.f, 0.f, 0.f, 0.f};
#pragma unroll
    for (int m = 0; m < 4; ++m) {
        float rowpart[4] = {0.f, 0.f, 0.f, 0.f};
#pragma unroll
        for (int n = 0; n < 4; ++n) {
#pragma unroll
            for (int r = 0; r < 4; ++r) {
                float v = exp2f(acc[m][n][r] * CEXP);
                rowpart[r] += v;
                colpart[n] += v;
            }
        }
#pragma unroll
        for (int r = 0; r < 4; ++r) {
            float t = rowpart[r];
            t += __shfl_xor(t, 1);
            t += __shfl_xor(t, 2);
            t += __shfl_xor(t, 4);
            t += __shfl_xor(t, 8);
            if (lrow == 0) lred[wc * 128 + wr * 64 + m * 16 + lk * 4 + r] = t;
        }
    }
#pragma unroll
    for (int n = 0; n < 4; ++n) {
        float t = colpart[n];
        t += __shfl_xor(t, 16);
        t += __shfl_xor(t, 32);
        if (lk == 0) lred[256 + wr * 128 + wc * 64 + n * 16 + lrow] = t;
    }
    __syncthreads();

    if (tid < 128) {
        gpart[(size_t)bj * (2 * NND) + m0 + tid] = lred[tid] + lred[128 + tid];
    } else if (m0 != n0) {
        const int c = tid - 128;
        gpart[(size_t)bi * (2 * NND) + n0 + c] = lred[256 + c] + lred[384 + c];
    }
}

// ---------------- fused normalize (rows i, i+8192) + diag dot -> fp8 (k-permuted) ----------------
__global__ void normalize_diag(const short* __restrict__ o, unsigned char* __restrict__ anq,
                               float* __restrict__ d12) {
    const int row = blockIdx.x;          // 0..8191
    const int t = threadIdx.x;           // 128 threads x 4 elems
    short4v va = ((const short4v*)(o + ((size_t)row << 9)))[t];
    short4v vb = ((const short4v*)(o + ((size_t)(row + NND) << 9)))[t];
    const float a0 = bf2f(va[0]), a1 = bf2f(va[1]), a2 = bf2f(va[2]), a3 = bf2f(va[3]);
    const float b0 = bf2f(vb[0]), b1 = bf2f(vb[1]), b2 = bf2f(vb[2]), b3 = bf2f(vb[3]);
    float ssa = a0 * a0 + a1 * a1 + a2 * a2 + a3 * a3;
    float ssb = b0 * b0 + b1 * b1 + b2 * b2 + b3 * b3;
    float sd  = a0 * b0 + a1 * b1 + a2 * b2 + a3 * b3;
    for (int m = 1; m < 64; m <<= 1) {
        ssa += __shfl_xor(ssa, m);
        ssb += __shfl_xor(ssb, m);
        sd  += __shfl_xor(sd, m);
    }
    __shared__ float part[6];
    if ((t & 63) == 0) {
        const int w = (t >> 6) * 3;
        part[w] = ssa; part[w + 1] = ssb; part[w + 2] = sd;
    }
    __syncthreads();
    const float sca = 1.f / fmaxf(sqrtf(part[0] + part[3]), 1e-12f);
    const float scb = 1.f / fmaxf(sqrtf(part[1] + part[4]), 1e-12f);
    if (t == 0) d12[row] = (part[2] + part[5]) * sca * scb;

    // permuted store: k-tile b (64), within: s = kk>>5, granule g = (kk&31)>>3, o = kk&7
    const int k = t * 4;
    const int bb = k >> 6, kk = k & 63;
    const int off = (bb << 6) + (((kk & 31) >> 3) << 4) + ((kk >> 5) << 3) + (kk & 7);
    int wa = __builtin_amdgcn_cvt_pk_fp8_f32(a0 * sca, a1 * sca, 0, false);
    wa = __builtin_amdgcn_cvt_pk_fp8_f32(a2 * sca, a3 * sca, wa, true);
    *(int*)(anq + (row << 9) + off) = wa;
    int wb = __builtin_amdgcn_cvt_pk_fp8_f32(b0 * scb, b1 * scb, 0, false);
    wb = __builtin_amdgcn_cvt_pk_fp8_f32(b2 * scb, b3 * scb, wb, true);
    *(int*)(anq + ((size_t)(row + NND) << 9) + off) = wb;
}

// ---------------- fused partial-reduce + loss: 32 blocks x 256 threads ----------------
// thread i: sum 128 slots for rows i and i+NND, compute loss term, block-reduce,
// one atomicAdd per block into out[0] (pre-zeroed by hipMemsetAsync).
__global__ void reduce_loss(const float* __restrict__ gpart, const float* __restrict__ d12,
                            float* __restrict__ out) {
    const int i = blockIdx.x * 256 + threadIdx.x;    // 0..8191
    float s1 = 0.f, s2 = 0.f;
#pragma unroll 8
    for (int sl = 0; sl < 128; ++sl) {
        s1 += gpart[(size_t)sl * (2 * NND) + i];
        s2 += gpart[(size_t)sl * (2 * NND) + NND + i];
    }
    float s = 0.5f * (logf(s1 - E2) + logf(s2 - E2)) - d12[i] * TAU_INV;
    for (int m = 1; m < 64; m <<= 1) s += __shfl_xor(s, m);
    __shared__ float part[4];
    const int lane = threadIdx.x & 63, w = threadIdx.x >> 6;
    if (lane == 0) part[w] = s;
    __syncthreads();
    if (threadIdx.x == 0)
        atomicAdd(out, (part[0] + part[1] + part[2] + part[3]) * (1.0f / (float)NND));
}

// ---------------- launch ----------------
extern "C" void kernel_launch(void* const* d_in, const int* in_sizes, int n_in,
                              void* d_out, int out_size, void* d_ws, size_t ws_size,
                              hipStream_t stream) {
    const float* z1 = (const float*)d_in[0];
    const float* z2 = (const float*)d_in[1];
    const float* w1 = (const float*)d_in[3];
    const float* b1 = (const float*)d_in[4];
    const float* w2 = (const float*)d_in[5];
    const float* b2 = (const float*)d_in[6];
    float* out = (float*)d_out;

    char* p = (char*)d_ws;
    const size_t MATB = (size_t)2 * NND * DHID * 2;   // 16 MB stacked bf16 matrix
    short* hb  = (short*)p;  p += MATB;
    short* obuf = (short*)p; p += MATB;
    unsigned char* anq = (unsigned char*)p; p += (size_t)2 * NND * DHID;  // stacked fp8
    float* gpart = (float*)p; p += (size_t)128 * 2 * NND * 4;             // 8 MB partials
    short* w1t = (short*)p;  p += 512 * 512 * 2;
    short* w2t = (short*)p;  p += 512 * 512 * 2;
    float* d12 = (float*)p;  p += NND * 4;
    if ((size_t)(p - (char*)d_ws) > ws_size) return;

    hipMemsetAsync(out, 0, sizeof(float), stream);

    transpose_cast2<<<128, 256, 0, stream>>>(w1, w2, w1t, w2t);
    gemm_nt<0><<<dim3(128, 4), 256, 0, stream>>>(z1, z2, nullptr, w1t, b1, hb);
    gemm_nt<1><<<dim3(128, 4), 256, 0, stream>>>(nullptr, nullptr, hb, w2t, b2, obuf);
    normalize_diag<<<NND, 128, 0, stream>>>(obuf, anq, d12);

    gemm_gram<<<8256, 256, 0, stream>>>(anq, gpart);
    reduce_loss<<<32, 256, 0, stream>>>(gpart, d12, out);
}